// Round 8
// baseline (377.021 us; speedup 1.0000x reference)
//
#include <hip/hip_runtime.h>

// Problem constants (fixed by reference setup_inputs)
#define BN 32768      // batch
#define DN 1024       // feature dim
#define CN 256        // num classes
#define RCAP 320      // max class size tracked (counts ~128 +/- 11)
#define NCH 32        // row chunks (streaming path)
#define CHR (BN/NCH)  // 1024 rows per chunk
#define NSL 8         // column slices
#define SLF (DN/NSL)  // 128 floats per slice

__device__ __forceinline__ float dot4(float4 a, float4 b) {
    return a.x*b.x + a.y*b.y + a.z*b.z + a.w*b.w;
}

// ===========================================================================
// STREAMING PATH (3 kernels). Rationale ledger:
//   scattered 4KB row gather pinned at ~1.75 TB/s across 5 kernels
//   (occupancy/ILP/depth/chain all null, R2-R7); sequential fill measured
//   6.9 TB/s. Streaming reads features twice sequentially (norm + accum)
//   but at ~3.5x the rate -> predicted net win over the 81 us fused gather.
// ===========================================================================

// --------------------------------------------------------------------------
// K_NORM: streaming row norms. 2048 blocks x 256 thr = 8192 waves; wave g
// handles rows g, g+8192, ... fully coalesced. rnorm[row] = 1/max(||x||,eps).
// --------------------------------------------------------------------------
__global__ void __launch_bounds__(256) k_norm(const float4* __restrict__ x4,
                                              float* __restrict__ rnorm) {
    const int lane = threadIdx.x & 63;
    const int gw = (int)((blockIdx.x * 256u + threadIdx.x) >> 6);
    for (int row = gw; row < BN; row += 8192) {
        const float4* b4 = x4 + (size_t)row * 256;
        const float4 v0 = b4[lane];
        const float4 v1 = b4[lane + 64];
        const float4 v2 = b4[lane + 128];
        const float4 v3 = b4[lane + 192];
        float ss = dot4(v0, v0) + dot4(v1, v1) + dot4(v2, v2) + dot4(v3, v3);
#pragma unroll
        for (int off = 32; off; off >>= 1) ss += __shfl_xor(ss, off, 64);
        if (lane == 0) rnorm[row] = 1.0f / fmaxf(sqrtf(ss), 1e-12f);
    }
}

// --------------------------------------------------------------------------
// K_STREAM: sequential-read accumulation with column-split class state.
// 256 blocks = 32 row-chunks x 8 column-slices (slice = bid&7 fast-varying,
// so the 8 blocks covering the same rows launch together and their reads
// union to full 4KB rows -> DRAM-page friendly). Each block:
//   LDS acc[256][128] (128 KB) = all classes x its 128 columns,
//   rows of its chunk processed in SEQUENTIAL order (32 consecutive rows
//   per block-iteration), each row's 512B slice scaled by rnorm and
//   LDS-atomicAdd'ed into acc[label] (lane l owns cols l,l+32,l+64,l+96
//   -> 32 distinct banks, conflict-free).
// Epilogue: non-atomic 128 KB partial write to partial[chunk][cls][cols].
// --------------------------------------------------------------------------
__global__ void __launch_bounds__(1024) k_stream(const float* __restrict__ xf,
                                                 const int* __restrict__ labels,
                                                 const float* __restrict__ rnorm,
                                                 float* __restrict__ partial) {
    __shared__ float acc[CN][SLF];        // 128 KB accumulators
    __shared__ unsigned char slab[CHR];   // 1 KB labels of this chunk
    __shared__ float rnv[CHR];            // 4 KB norms of this chunk

    const int bid = blockIdx.x;
    const int slice = bid & (NSL - 1);
    const int chunk = bid >> 3;
    const int t = threadIdx.x;

    for (int i = t; i < CN * SLF; i += 1024) ((float*)acc)[i] = 0.0f;
    if (t < CHR / 4) {
        const int4 lv = ((const int4*)(labels + chunk * CHR))[t];
        ((uchar4*)slab)[t] = make_uchar4((unsigned char)lv.x, (unsigned char)lv.y,
                                         (unsigned char)lv.z, (unsigned char)lv.w);
        ((float4*)rnv)[t] = ((const float4*)(rnorm + chunk * CHR))[t];
    }
    __syncthreads();

    const int wave = t >> 6, lane = t & 63;
    const int half = lane >> 5, cl = lane & 31;

    for (int it = 0; it < CHR / 32; ++it) {
        const int rloc = it * 32 + wave * 2 + half;      // 32 consecutive rows/iter
        const float* base = xf + (size_t)(chunk * CHR + rloc) * DN + slice * SLF;
        const float v0 = base[cl];
        const float v1 = base[cl + 32];
        const float v2 = base[cl + 64];
        const float v3 = base[cl + 96];
        const float rn = rnv[rloc];        // broadcast (uniform per half-wave)
        const int lab = slab[rloc];
        atomicAdd(&acc[lab][cl],      v0 * rn);   // banks 0..31 distinct
        atomicAdd(&acc[lab][cl + 32], v1 * rn);
        atomicAdd(&acc[lab][cl + 64], v2 * rn);
        atomicAdd(&acc[lab][cl + 96], v3 * rn);
    }
    __syncthreads();

    // partial[chunk][cls][slice*SLF + col], each element written exactly once
    for (int u = t; u < CN * (SLF / 4); u += 1024) {
        const int cls = u >> 5, q = u & 31;
        ((float4*)partial)[((size_t)chunk * CN + cls) * (DN / 4) + slice * (SLF / 4) + q]
            = ((const float4*)acc[cls])[q];
    }
}

// --------------------------------------------------------------------------
// K_FINISH: one block (1024 thr / 16 waves) per class.
//  1) reduce 32 chunk partials -> S (thread t owns col t), Sl[] in LDS
//  2) ||S||^2 block reduce
//  3) label stage + ballot compaction -> sic[], rnl[] (verbatim from the
//     proven R7 kernel)
//  4) wave-parallel exclusion corrections (R7 structure, S from Sl)
//  5) single pre-scaled atomicAdd into out
// --------------------------------------------------------------------------
__global__ void __launch_bounds__(1024) k_finish(const float4* __restrict__ x4,
                                                 const int* __restrict__ labels,
                                                 const float* __restrict__ rnorm,
                                                 const float* __restrict__ partial,
                                                 float* __restrict__ out) {
    __shared__ unsigned int packed[BN / 4];       // 32 KB
    __shared__ unsigned long long smask[BN / 64]; // 4 KB
    __shared__ int sic[RCAP];
    __shared__ float rnl[RCAP];
    __shared__ int wcnt[16];
    __shared__ float Sl[DN];                      // 4 KB class sum vector
    __shared__ float wred[16];
    __shared__ float dacc_s;

    const int c = blockIdx.x;
    const int t = threadIdx.x;
    const int wave = t >> 6, lane = t & 63;

    // ---- stage labels packed as bytes ----
    for (int w = t; w < BN / 4; w += 1024) {
        const int4 v = ((const int4*)labels)[w];
        packed[w] = (unsigned int)(v.x & 255)
                  | ((unsigned int)(v.y & 255) << 8)
                  | ((unsigned int)(v.z & 255) << 16)
                  | ((unsigned int)(v.w & 255) << 24);
    }
    if (t == 0) dacc_s = 0.0f;

    // ---- reduce partials: thread t owns column t ----
    float Sv = 0.0f;
    for (int ch = 0; ch < NCH; ++ch)
        Sv += partial[((size_t)ch * CN + c) * DN + t];
    Sl[t] = Sv;

    // ---- ||S||^2 partial ----
    float dsq = Sv * Sv;
#pragma unroll
    for (int off = 32; off; off >>= 1) dsq += __shfl_xor(dsq, off, 64);
    if (lane == 0) wred[wave] = dsq;
    __syncthreads();   // packed, Sl, wred visible

    const unsigned long long lt = (lane == 0) ? 0ull : (~0ull >> (64 - lane));
    const int ch0 = wave * 32, ch1 = ch0 + 32;

    // ---- pass 1: count + save ballot masks ----
    int cnt = 0;
    for (int ch = ch0; ch < ch1; ++ch) {
        const int gi = ch * 64 + lane;
        const int lab = (packed[gi >> 2] >> ((gi & 3) * 8)) & 255;
        const unsigned long long mask = __ballot(lab == c);
        if (lane == 0) smask[ch] = mask;
        cnt += __popcll(mask);
    }
    if (lane == 0) wcnt[wave] = cnt;
    __syncthreads();

    int base = 0, ntot = 0;
    for (int w2 = 0; w2 < 16; ++w2) {
        const int v = wcnt[w2];
        if (w2 < wave) base += v;
        ntot += v;
    }

    // ---- pass 2: ordered member list + norms ----
    for (int ch = ch0; ch < ch1; ++ch) {
        const unsigned long long mask = smask[ch];
        if ((mask >> lane) & 1ull) {
            const int pos = base + __popcll(mask & lt);
            if (pos < RCAP) {
                const int gi = ch * 64 + lane;
                sic[pos] = gi;
                rnl[pos] = rnorm[gi];
            }
        }
        base += __popcll(mask);
    }
    __syncthreads();

    const int n = ntot;
    if (n >= 2) {
        float s2 = 0.0f;
        for (int w2 = 0; w2 < 16; ++w2) s2 += wred[w2];
        const int nn = min(n, RCAP);
        const int nlim = nn;   // == n unless overflow (never at RCAP=320)

        // ---- wave-parallel exclusion corrections (no intra-loop barriers) ----
        const float4* Sl4 = (const float4*)Sl;
        for (int p = wave; p < nn; p += 16) {
            const int j = sic[p];
            if (j >= nlim) continue;
            const int k = sic[j];
            const float4* bi = x4 + (size_t)j * 256;
            const float4* bk = x4 + (size_t)k * 256;
            const float4 xi0 = bi[lane], xi1 = bi[lane + 64],
                         xi2 = bi[lane + 128], xi3 = bi[lane + 192];
            const float4 xk0 = bk[lane], xk1 = bk[lane + 64],
                         xk2 = bk[lane + 128], xk3 = bk[lane + 192];
            const float4 S0 = Sl4[lane], S1 = Sl4[lane + 64],
                         S2 = Sl4[lane + 128], S3 = Sl4[lane + 192];
            float d0 = dot4(xi0, S0) + dot4(xi1, S1) + dot4(xi2, S2) + dot4(xi3, S3);
            float d1 = dot4(xi0, xk0) + dot4(xi1, xk1) + dot4(xi2, xk2) + dot4(xi3, xk3);
            float d2 = dot4(xk0, S0) + dot4(xk1, S1) + dot4(xk2, S2) + dot4(xk3, S3);
            float d3 = dot4(xk0, xk0) + dot4(xk1, xk1) + dot4(xk2, xk2) + dot4(xk3, xk3);
#pragma unroll
            for (int off = 32; off; off >>= 1) {
                d0 += __shfl_xor(d0, off, 64);
                d1 += __shfl_xor(d1, off, 64);
                d2 += __shfl_xor(d2, off, 64);
                d3 += __shfl_xor(d3, off, 64);
            }
            if (lane == 0) {
                const float rni = rnl[p];
                const float rnk = rnl[j];
                const float fiS  = rni * d0;
                const float fifk = rni * rnk * d1;
                const float Sfk  = rnk * d2;
                const float fk2  = rnk * rnk * d3;
                const float nf = (float)n;
                const float dd = nf - 1.0f;
                const float naive = -2.0f * fiS / nf + s2 / (nf * nf);
                const float corr  = -2.0f * (fiS - fifk) / dd
                                  + (s2 - 2.0f * Sfk + fk2) / (dd * dd);
                atomicAdd(&dacc_s, corr - naive);
            }
        }
        __syncthreads();
        if (t == 0) {
            const float nf = (float)n;
            const float total = (nf - s2 / nf) + dacc_s;
            atomicAdd(out, total * (1.0f / DN) * (0.0005f / (float)BN));
        }
    }
}

// ===========================================================================
// FALLBACK: the proven round-7 fused kernel (81 us) -- used if ws_size is
// smaller than the streaming path needs (33.7 MB).
// ===========================================================================
__global__ void __launch_bounds__(1024) k_all(const float4* __restrict__ x4,
                                              const int* __restrict__ labels,
                                              float* __restrict__ out) {
    __shared__ unsigned int packed[BN / 4];
    __shared__ unsigned long long smask[BN / 64];
    __shared__ int sic[RCAP];
    __shared__ float rnl[RCAP];
    __shared__ int wcnt[16];
    __shared__ float fa[(DN / 4) * 5];
    __shared__ float wred[4];
    __shared__ float dacc_s;

    const int c = blockIdx.x;
    const int t = threadIdx.x;

    for (int w = t; w < BN / 4; w += 1024) {
        const int4 v = ((const int4*)labels)[w];
        packed[w] = (unsigned int)(v.x & 255)
                  | ((unsigned int)(v.y & 255) << 8)
                  | ((unsigned int)(v.z & 255) << 16)
                  | ((unsigned int)(v.w & 255) << 24);
    }
    for (int i = t; i < (DN / 4) * 5; i += 1024) fa[i] = 0.0f;
    if (t == 0) dacc_s = 0.0f;
    __syncthreads();

    const int wave = t >> 6, lane = t & 63;
    const unsigned long long lt = (lane == 0) ? 0ull : (~0ull >> (64 - lane));
    const int ch0 = wave * 32, ch1 = ch0 + 32;

    int cnt = 0;
    for (int ch = ch0; ch < ch1; ++ch) {
        const int gi = ch * 64 + lane;
        const int lab = (packed[gi >> 2] >> ((gi & 3) * 8)) & 255;
        const unsigned long long mask = __ballot(lab == c);
        if (lane == 0) smask[ch] = mask;
        cnt += __popcll(mask);
    }
    if (lane == 0) wcnt[wave] = cnt;
    __syncthreads();

    int base = 0, ntot = 0;
    for (int w2 = 0; w2 < 16; ++w2) {
        const int v = wcnt[w2];
        if (w2 < wave) base += v;
        ntot += v;
    }

    for (int ch = ch0; ch < ch1; ++ch) {
        const unsigned long long mask = smask[ch];
        if ((mask >> lane) & 1ull) {
            const int pos = base + __popcll(mask & lt);
            if (pos < RCAP) sic[pos] = ch * 64 + lane;
        }
        base += __popcll(mask);
    }
    __syncthreads();

    const int nn = min(ntot, RCAP);
    float4 a0 = make_float4(0.f, 0.f, 0.f, 0.f), a1 = a0, a2 = a0, a3 = a0;
    for (int r = wave; r < nn; r += 16) {
        const int row = sic[r];
        const float4* b4 = x4 + (size_t)row * 256;
        const float4 v0 = b4[lane];
        const float4 v1 = b4[lane + 64];
        const float4 v2 = b4[lane + 128];
        const float4 v3 = b4[lane + 192];
        float ss = dot4(v0, v0) + dot4(v1, v1) + dot4(v2, v2) + dot4(v3, v3);
#pragma unroll
        for (int off = 32; off; off >>= 1) ss += __shfl_xor(ss, off, 64);
        const float rn = 1.0f / fmaxf(sqrtf(ss), 1e-12f);
        if (lane == 0) rnl[r] = rn;
        a0.x += v0.x * rn; a0.y += v0.y * rn; a0.z += v0.z * rn; a0.w += v0.w * rn;
        a1.x += v1.x * rn; a1.y += v1.y * rn; a1.z += v1.z * rn; a1.w += v1.w * rn;
        a2.x += v2.x * rn; a2.y += v2.y * rn; a2.z += v2.z * rn; a2.w += v2.w * rn;
        a3.x += v3.x * rn; a3.y += v3.y * rn; a3.z += v3.z * rn; a3.w += v3.w * rn;
    }

    {
        const int q0 = lane, q1 = lane + 64, q2 = lane + 128, q3 = lane + 192;
        atomicAdd(&fa[5 * q0 + 0], a0.x); atomicAdd(&fa[5 * q0 + 1], a0.y);
        atomicAdd(&fa[5 * q0 + 2], a0.z); atomicAdd(&fa[5 * q0 + 3], a0.w);
        atomicAdd(&fa[5 * q1 + 0], a1.x); atomicAdd(&fa[5 * q1 + 1], a1.y);
        atomicAdd(&fa[5 * q1 + 2], a1.z); atomicAdd(&fa[5 * q1 + 3], a1.w);
        atomicAdd(&fa[5 * q2 + 0], a2.x); atomicAdd(&fa[5 * q2 + 1], a2.y);
        atomicAdd(&fa[5 * q2 + 2], a2.z); atomicAdd(&fa[5 * q2 + 3], a2.w);
        atomicAdd(&fa[5 * q3 + 0], a3.x); atomicAdd(&fa[5 * q3 + 1], a3.y);
        atomicAdd(&fa[5 * q3 + 2], a3.z); atomicAdd(&fa[5 * q3 + 3], a3.w);
    }
    __syncthreads();

    float d = 0.0f;
    if (t < 256) {
        float4 Sq;
        Sq.x = fa[5 * t + 0]; Sq.y = fa[5 * t + 1];
        Sq.z = fa[5 * t + 2]; Sq.w = fa[5 * t + 3];
        d = dot4(Sq, Sq);
    }
    if (wave < 4) {
#pragma unroll
        for (int off = 32; off; off >>= 1) d += __shfl_xor(d, off, 64);
        if (lane == 0) wred[wave] = d;
    }
    __syncthreads();

    const int n = ntot;
    if (n >= 2) {
        const float s2 = wred[0] + wred[1] + wred[2] + wred[3];
        const int nlim = min(n, nn);
        for (int p = wave; p < nn; p += 16) {
            const int j = sic[p];
            if (j >= nlim) continue;
            const int k = sic[j];
            const float4* bi = x4 + (size_t)j * 256;
            const float4* bk = x4 + (size_t)k * 256;
            const float4 xi0 = bi[lane], xi1 = bi[lane + 64],
                         xi2 = bi[lane + 128], xi3 = bi[lane + 192];
            const float4 xk0 = bk[lane], xk1 = bk[lane + 64],
                         xk2 = bk[lane + 128], xk3 = bk[lane + 192];
            float4 S0, S1, S2, S3;
            {
                const int q0 = lane, q1 = lane + 64, q2 = lane + 128, q3 = lane + 192;
                S0.x = fa[5*q0+0]; S0.y = fa[5*q0+1]; S0.z = fa[5*q0+2]; S0.w = fa[5*q0+3];
                S1.x = fa[5*q1+0]; S1.y = fa[5*q1+1]; S1.z = fa[5*q1+2]; S1.w = fa[5*q1+3];
                S2.x = fa[5*q2+0]; S2.y = fa[5*q2+1]; S2.z = fa[5*q2+2]; S2.w = fa[5*q2+3];
                S3.x = fa[5*q3+0]; S3.y = fa[5*q3+1]; S3.z = fa[5*q3+2]; S3.w = fa[5*q3+3];
            }
            float d0 = dot4(xi0, S0) + dot4(xi1, S1) + dot4(xi2, S2) + dot4(xi3, S3);
            float d1 = dot4(xi0, xk0) + dot4(xi1, xk1) + dot4(xi2, xk2) + dot4(xi3, xk3);
            float d2 = dot4(xk0, S0) + dot4(xk1, S1) + dot4(xk2, S2) + dot4(xk3, S3);
            float d3 = dot4(xk0, xk0) + dot4(xk1, xk1) + dot4(xk2, xk2) + dot4(xk3, xk3);
#pragma unroll
            for (int off = 32; off; off >>= 1) {
                d0 += __shfl_xor(d0, off, 64);
                d1 += __shfl_xor(d1, off, 64);
                d2 += __shfl_xor(d2, off, 64);
                d3 += __shfl_xor(d3, off, 64);
            }
            if (lane == 0) {
                const float rni = rnl[p];
                const float rnk = rnl[j];
                const float fiS  = rni * d0;
                const float fifk = rni * rnk * d1;
                const float Sfk  = rnk * d2;
                const float fk2  = rnk * rnk * d3;
                const float nf = (float)n;
                const float dd = nf - 1.0f;
                const float naive = -2.0f * fiS / nf + s2 / (nf * nf);
                const float corr  = -2.0f * (fiS - fifk) / dd
                                  + (s2 - 2.0f * Sfk + fk2) / (dd * dd);
                atomicAdd(&dacc_s, corr - naive);
            }
        }
        __syncthreads();
        if (t == 0) {
            const float nf = (float)n;
            const float total = (nf - s2 / nf) + dacc_s;
            atomicAdd(out, total * (1.0f / DN) * (0.0005f / (float)BN));
        }
    }
}

extern "C" void kernel_launch(void* const* d_in, const int* in_sizes, int n_in,
                              void* d_out, int out_size, void* d_ws, size_t ws_size,
                              hipStream_t stream) {
    const float4* x4 = (const float4*)d_in[0];
    const float* xf = (const float*)d_in[0];
    const int* labels = (const int*)d_in[1];
    float* out = (float*)d_out;
    char* ws = (char*)d_ws;

    const size_t P_OFF = 131072;                               // rnorm: 128 KB
    const size_t NEED = P_OFF + (size_t)NCH * CN * DN * 4;     // + 32 MB partials

    hipMemsetAsync(out, 0, sizeof(float), stream);
    if (ws_size >= NEED) {
        float* rnorm = (float*)ws;
        float* partial = (float*)(ws + P_OFF);
        k_norm<<<2048, 256, 0, stream>>>(x4, rnorm);
        k_stream<<<NCH * NSL, 1024, 0, stream>>>(xf, labels, rnorm, partial);
        k_finish<<<CN, 1024, 0, stream>>>(x4, labels, rnorm, partial, out);
    } else {
        k_all<<<CN, 1024, 0, stream>>>(x4, labels, out);
    }
}

// Round 9
// 219.260 us; speedup vs baseline: 1.7195x; 1.7195x over previous
//
#include <hip/hip_runtime.h>

// Problem constants (fixed by reference setup_inputs)
#define BN 32768      // batch
#define DN 1024       // feature dim
#define CN 256        // num classes
#define RCAP 320      // max class size tracked (counts ~128 +/- 11; 320 = ~17 sigma)

__device__ __forceinline__ float dot4(float4 a, float4 b) {
    return a.x*b.x + a.y*b.y + a.z*b.z + a.w*b.w;
}

// ---------------------------------------------------------------------------
// K_ALL (round-7 proven best, 81 us): one block (1024 thr / 16 waves) per
// class. Fully fused, read-once.
// Measurement ledger (all on this problem, MI355X):
//   - scattered 4KB-row gather pinned at ~1.75 TB/s device-wide regardless
//     of occupancy (R2: 32 waves/CU null), chain removal (R4 null), load
//     depth (R5 null), unrolling (R3/R5 ~neutral).
//   - streaming column-split alternative (R8): 177 us @ 575 GB/s -- far
//     worse (4B-granule loads + LDS-atomic RMW latency chain).
//   - fused SERIAL corrections cost +12 us worst-block tail (R6); fixed
//     here by wave-parallel corrections (no intra-loop barriers).
// Phases:
//  1) stage labels packed as bytes (32 KB LDS)
//  2) compaction: ballot-count saving per-chunk masks (smask); replay masks
//     for the ordered member list sic[] (no label re-read)
//  3) gather: wave w takes positions r = w, w+16, ...: load full 4 KB row,
//     xor-shuffle row norm, rnl[r] = rn, accumulate x*rn in wave regs
//  4) block-reduce wave accumulators via stride-5-padded LDS atomics
//     (conflict-free; SQ_LDS_BANK_CONFLICT == 0 in all rounds)
//  5) corrections WAVE-PARALLEL: wave w handles p = w, w+16, ... with
//     exclusion iff j=sic[p] < n; k=sic[j]; S read from padded fa (stride-5
//     -> gcd(5,32)=1 walks all banks, 2 lanes/bank = free)
//  6) single pre-scaled atomicAdd into out. 2 dispatches total.
// ---------------------------------------------------------------------------
__global__ void __launch_bounds__(1024) k_all(const float4* __restrict__ x4,
                                              const int* __restrict__ labels,
                                              float* __restrict__ out) {
    __shared__ unsigned int packed[BN / 4];       // 32 KB: 4 labels per word
    __shared__ unsigned long long smask[BN / 64]; // 4 KB: per-chunk ballot masks
    __shared__ int sic[RCAP];                     // ordered member list (rows)
    __shared__ float rnl[RCAP];                   // 1/||x_row|| per position
    __shared__ int wcnt[16];
    __shared__ float fa[(DN / 4) * 5];            // 5 KB, stride-5 padded quads
    __shared__ float wred[4];
    __shared__ float dacc_s;                      // correction delta accumulator

    const int c = blockIdx.x;
    const int t = threadIdx.x;

    // ---- stage labels (8192 words / 1024 thr = 8 int4 loads each) ----
    for (int w = t; w < BN / 4; w += 1024) {
        const int4 v = ((const int4*)labels)[w];
        packed[w] = (unsigned int)(v.x & 255)
                  | ((unsigned int)(v.y & 255) << 8)
                  | ((unsigned int)(v.z & 255) << 16)
                  | ((unsigned int)(v.w & 255) << 24);
    }
    for (int i = t; i < (DN / 4) * 5; i += 1024) fa[i] = 0.0f;
    if (t == 0) dacc_s = 0.0f;
    __syncthreads();

    const int wave = t >> 6, lane = t & 63;
    const unsigned long long lt = (lane == 0) ? 0ull : (~0ull >> (64 - lane));
    const int ch0 = wave * 32, ch1 = ch0 + 32;  // 32 chunks of 64 per wave

    // ---- pass 1: count + save ballot masks ----
    int cnt = 0;
    for (int ch = ch0; ch < ch1; ++ch) {
        const int gi = ch * 64 + lane;
        const int lab = (packed[gi >> 2] >> ((gi & 3) * 8)) & 255;
        const unsigned long long mask = __ballot(lab == c);
        if (lane == 0) smask[ch] = mask;
        cnt += __popcll(mask);
    }
    if (lane == 0) wcnt[wave] = cnt;
    __syncthreads();

    int base = 0, ntot = 0;
    for (int w2 = 0; w2 < 16; ++w2) {
        const int v = wcnt[w2];
        if (w2 < wave) base += v;
        ntot += v;
    }

    // ---- pass 2: ordered member list from saved masks ----
    for (int ch = ch0; ch < ch1; ++ch) {
        const unsigned long long mask = smask[ch];   // LDS broadcast
        if ((mask >> lane) & 1ull) {
            const int pos = base + __popcll(mask & lt);
            if (pos < RCAP) sic[pos] = ch * 64 + lane;
        }
        base += __popcll(mask);
    }
    __syncthreads();

    // ---- gather + row norm + scaled accumulate (1 row / wave-iteration) ----
    const int nn = min(ntot, RCAP);
    float4 a0 = make_float4(0.f, 0.f, 0.f, 0.f), a1 = a0, a2 = a0, a3 = a0;
    for (int r = wave; r < nn; r += 16) {
        const int row = sic[r];
        const float4* b4 = x4 + (size_t)row * 256;
        const float4 v0 = b4[lane];
        const float4 v1 = b4[lane + 64];
        const float4 v2 = b4[lane + 128];
        const float4 v3 = b4[lane + 192];
        float ss = dot4(v0, v0) + dot4(v1, v1) + dot4(v2, v2) + dot4(v3, v3);
#pragma unroll
        for (int off = 32; off; off >>= 1) ss += __shfl_xor(ss, off, 64);
        const float rn = 1.0f / fmaxf(sqrtf(ss), 1e-12f);
        if (lane == 0) rnl[r] = rn;
        a0.x += v0.x * rn; a0.y += v0.y * rn; a0.z += v0.z * rn; a0.w += v0.w * rn;
        a1.x += v1.x * rn; a1.y += v1.y * rn; a1.z += v1.z * rn; a1.w += v1.w * rn;
        a2.x += v2.x * rn; a2.y += v2.y * rn; a2.z += v2.z * rn; a2.w += v2.w * rn;
        a3.x += v3.x * rn; a3.y += v3.y * rn; a3.z += v3.z * rn; a3.w += v3.w * rn;
    }

    // ---- reduce 16 waves into padded LDS (quad q at fa[5q..5q+3]) ----
    {
        const int q0 = lane, q1 = lane + 64, q2 = lane + 128, q3 = lane + 192;
        atomicAdd(&fa[5 * q0 + 0], a0.x); atomicAdd(&fa[5 * q0 + 1], a0.y);
        atomicAdd(&fa[5 * q0 + 2], a0.z); atomicAdd(&fa[5 * q0 + 3], a0.w);
        atomicAdd(&fa[5 * q1 + 0], a1.x); atomicAdd(&fa[5 * q1 + 1], a1.y);
        atomicAdd(&fa[5 * q1 + 2], a1.z); atomicAdd(&fa[5 * q1 + 3], a1.w);
        atomicAdd(&fa[5 * q2 + 0], a2.x); atomicAdd(&fa[5 * q2 + 1], a2.y);
        atomicAdd(&fa[5 * q2 + 2], a2.z); atomicAdd(&fa[5 * q2 + 3], a2.w);
        atomicAdd(&fa[5 * q3 + 0], a3.x); atomicAdd(&fa[5 * q3 + 1], a3.y);
        atomicAdd(&fa[5 * q3 + 2], a3.z); atomicAdd(&fa[5 * q3 + 3], a3.w);
    }
    __syncthreads();

    // ---- ||S||^2 (threads t<256 hold one quad each, 4-wave reduce) ----
    float d = 0.0f;
    if (t < 256) {
        float4 Sq;
        Sq.x = fa[5 * t + 0]; Sq.y = fa[5 * t + 1];
        Sq.z = fa[5 * t + 2]; Sq.w = fa[5 * t + 3];
        d = dot4(Sq, Sq);
    }
    if (wave < 4) {
#pragma unroll
        for (int off = 32; off; off >>= 1) d += __shfl_xor(d, off, 64);
        if (lane == 0) wred[wave] = d;
    }
    __syncthreads();

    const int n = ntot;
    if (n >= 2) {                       // uniform across block
        const float s2 = wred[0] + wred[1] + wred[2] + wred[3];
        const int nlim = min(n, nn);

        // ---- WAVE-PARALLEL exclusion corrections (no intra-loop barriers) ----
        for (int p = wave; p < nn; p += 16) {
            const int j = sic[p];
            if (j >= nlim) continue;    // no exclusion for this member (wave-uniform)
            const int k = sic[j];       // member at in-class position j
            const float4* bi = x4 + (size_t)j * 256;
            const float4* bk = x4 + (size_t)k * 256;
            const float4 xi0 = bi[lane], xi1 = bi[lane + 64],
                         xi2 = bi[lane + 128], xi3 = bi[lane + 192];
            const float4 xk0 = bk[lane], xk1 = bk[lane + 64],
                         xk2 = bk[lane + 128], xk3 = bk[lane + 192];
            float4 S0, S1, S2, S3;
            {
                const int q0 = lane, q1 = lane + 64, q2 = lane + 128, q3 = lane + 192;
                S0.x = fa[5*q0+0]; S0.y = fa[5*q0+1]; S0.z = fa[5*q0+2]; S0.w = fa[5*q0+3];
                S1.x = fa[5*q1+0]; S1.y = fa[5*q1+1]; S1.z = fa[5*q1+2]; S1.w = fa[5*q1+3];
                S2.x = fa[5*q2+0]; S2.y = fa[5*q2+1]; S2.z = fa[5*q2+2]; S2.w = fa[5*q2+3];
                S3.x = fa[5*q3+0]; S3.y = fa[5*q3+1]; S3.z = fa[5*q3+2]; S3.w = fa[5*q3+3];
            }
            float d0 = dot4(xi0, S0) + dot4(xi1, S1) + dot4(xi2, S2) + dot4(xi3, S3);
            float d1 = dot4(xi0, xk0) + dot4(xi1, xk1) + dot4(xi2, xk2) + dot4(xi3, xk3);
            float d2 = dot4(xk0, S0) + dot4(xk1, S1) + dot4(xk2, S2) + dot4(xk3, S3);
            float d3 = dot4(xk0, xk0) + dot4(xk1, xk1) + dot4(xk2, xk2) + dot4(xk3, xk3);
#pragma unroll
            for (int off = 32; off; off >>= 1) {
                d0 += __shfl_xor(d0, off, 64);
                d1 += __shfl_xor(d1, off, 64);
                d2 += __shfl_xor(d2, off, 64);
                d3 += __shfl_xor(d3, off, 64);
            }
            if (lane == 0) {
                const float rni = rnl[p];   // norm of row j (position p)
                const float rnk = rnl[j];   // norm of row k (position j)
                const float fiS  = rni * d0;
                const float fifk = rni * rnk * d1;
                const float Sfk  = rnk * d2;
                const float fk2  = rnk * rnk * d3;
                const float nf = (float)n;
                const float dd = nf - 1.0f;
                const float naive = -2.0f * fiS / nf + s2 / (nf * nf);
                const float corr  = -2.0f * (fiS - fifk) / dd
                                  + (s2 - 2.0f * Sfk + fk2) / (dd * dd);
                atomicAdd(&dacc_s, corr - naive);
            }
        }
        __syncthreads();   // all waves' deltas landed in dacc_s
        if (t == 0) {
            const float nf = (float)n;
            const float total = (nf - s2 / nf) + dacc_s;
            atomicAdd(out, total * (1.0f / DN) * (0.0005f / (float)BN));
        }
    }
}

extern "C" void kernel_launch(void* const* d_in, const int* in_sizes, int n_in,
                              void* d_out, int out_size, void* d_ws, size_t ws_size,
                              hipStream_t stream) {
    const float4* x4 = (const float4*)d_in[0];
    const int* labels = (const int*)d_in[1];
    float* out = (float*)d_out;

    hipMemsetAsync(out, 0, sizeof(float), stream);
    k_all<<<CN, 1024, 0, stream>>>(x4, labels, out);
}